// Round 14
// baseline (40.384 us; speedup 1.0000x reference)
//
#include <hip/hip_runtime.h>
#include <hip/hip_bf16.h>

typedef __attribute__((ext_vector_type(8)))  short  short8_t;
typedef __attribute__((ext_vector_type(4)))  float  float4_t;
typedef __attribute__((ext_vector_type(16))) float  f32x16_t;
typedef __attribute__((ext_vector_type(4)))  int    int4_t;
typedef __attribute__((ext_vector_type(2)))  unsigned int uint2_t;

// f32 -> bf16 RNE (bit-twiddle; prepass/fallback)
__device__ __forceinline__ unsigned short f2bf(float f) {
    unsigned int u = __builtin_bit_cast(unsigned int, f);
    u += 0x7FFFu + ((u >> 16) & 1u);
    return (unsigned short)(u >> 16);
}
__device__ __forceinline__ unsigned int cvtpk(float a, float b) {
    return (unsigned int)f2bf(a) | ((unsigned int)f2bf(b) << 16);
}
// HW packed convert (no builtin on gfx950)
__device__ __forceinline__ unsigned int cvtpk_hw(float a, float b) {
    unsigned int r;
    asm("v_cvt_pk_bf16_f32 %0, %1, %2" : "=v"(r) : "v"(a), "v"(b));
    return r;
}
// lane i (i<32) <-> lane i+32: newX=[X.lo,Y.lo], newY=[X.hi,Y.hi]
__device__ __forceinline__ void plane32_swap(unsigned int& a, unsigned int& b) {
    asm("v_permlane32_swap_b32 %0, %1" : "+v"(a), "+v"(b));
}
// pinned 16B loads (compiler cannot sink/reorder vs volatile asm)
__device__ __forceinline__ void gld16(int4_t& d, const void* p) {
    asm volatile("global_load_dwordx4 %0, %1, off" : "=&v"(d) : "v"(p) : "memory");
}
#define GLD16O(d, p, OFF) \
    asm volatile("global_load_dwordx4 %0, %1, off offset:" OFF : "=&v"(d) : "v"(p) : "memory")
// counted wait: 5 youngest (next-step 4 W2 + 1 af) stay in flight
__device__ __forceinline__ void wait5() {
    asm volatile("s_waitcnt vmcnt(5)" ::: "memory");
    __builtin_amdgcn_sched_barrier(0);
}
__device__ __forceinline__ void wait_all() {
    asm volatile("s_waitcnt vmcnt(0)" ::: "memory");
    __builtin_amdgcn_sched_barrier(0);
}

// ---- prepass ----
// W2t granule layout (32x32x16 A-frags): granule g = (ks*8+et)*64+lane,
//   value = W2[et*32+(lane&31)][ks*16+(lane>>5)*8 .. +8)  (bf16 x8, 16B)
// W1b: 1024 x 8 bf16 row-major
__global__ void prep_kernel(const float* __restrict__ W2, const float* __restrict__ W1,
                            unsigned short* __restrict__ W2t, unsigned short* __restrict__ W1b) {
    const int bid = blockIdx.x, tid = threadIdx.x;
    if (bid < 128) {
        const int g   = bid * 256 + tid;
        const int l   = g & 63;
        const int pos = g >> 6;                   // ks*8+et
        const int ks  = pos >> 3;
        const int et  = pos & 7;
        const int e   = et * 32 + (l & 31);
        const int f0  = ks * 16 + (l >> 5) * 8;
        const float* src = W2 + (size_t)e * 1024 + f0;
        const float4_t v0 = *reinterpret_cast<const float4_t*>(src);
        const float4_t v1 = *reinterpret_cast<const float4_t*>(src + 4);
        int4_t p;
        p[0] = (int)cvtpk(v0[0], v0[1]);
        p[1] = (int)cvtpk(v0[2], v0[3]);
        p[2] = (int)cvtpk(v1[0], v1[1]);
        p[3] = (int)cvtpk(v1[2], v1[3]);
        *reinterpret_cast<int4_t*>(W2t + (size_t)g * 8) = p;
    } else {
        const int base = tid * 32;
        #pragma unroll
        for (int it = 0; it < 8; ++it) {
            const float4_t v = *reinterpret_cast<const float4_t*>(W1 + base + it * 4);
            uint2_t p;
            p[0] = cvtpk(v[0], v[1]);
            p[1] = cvtpk(v[2], v[3]);
            *reinterpret_cast<uint2_t*>(W1b + base + it * 4) = p;
        }
    }
}

// ---- fused, zero-LDS, zero-barrier, 32x32x16; wave = 64 rows x 64 cols (M-reuse x2) ----
// Per 32-f step: 1 af + 4 W2 loads; 2 h-MFMA (+2 htr) -> bf[mh][kw]; 8 main MFMA.
// 2048 waves (512 blocks x 4, block shares coltile -> L1-hot W2).
template <bool WSOK>
__global__ __launch_bounds__(256, 2)
void ffq_kernel(const float* __restrict__ x,
                const float* __restrict__ theta,
                const float* __restrict__ W1f,
                const unsigned short* __restrict__ W1b,
                const float* __restrict__ W2f,
                const unsigned short* __restrict__ W2t,
                float* __restrict__ out)
{
    const int tid  = threadIdx.x;
    const int lane = tid & 63;
    const int w    = tid >> 6;
    const int bid  = blockIdx.x;
    const int ct      = bid & 3;                  // coltile (64 cols), shared in block
    const int mtile   = (bid >> 2) * 4 + w;       // 512 row-tiles of 64
    const int rowbase = mtile * 64;
    const int m  = lane & 31;
    const int hi = lane >> 5;

    // ---- q B-frags (2 m-halves): lane<32 holds q[row][0..7]; hi lanes ZERO (K pad) ----
    short8_t qf0 = {0,0,0,0,0,0,0,0}, qf1 = {0,0,0,0,0,0,0,0};
    if (lane < 32) {
        #pragma unroll
        for (int mh = 0; mh < 2; ++mh) {
            const float* xp = x + (size_t)(rowbase + mh * 32 + m) * 256;
            const float4_t x0 = *reinterpret_cast<const float4_t*>(xp);
            const float4_t x1 = *reinterpret_cast<const float4_t*>(xp + 4);
            float qv[8];
            #pragma unroll
            for (int j = 0; j < 4; ++j) {
                qv[j]     = __cosf(x0[j]) * __cosf(theta[j]);
                qv[4 + j] = __cosf(x1[j]) * __cosf(theta[4 + j]);
            }
            int4_t pq;
            pq[0] = (int)cvtpk(qv[0], qv[1]);
            pq[1] = (int)cvtpk(qv[2], qv[3]);
            pq[2] = (int)cvtpk(qv[4], qv[5]);
            pq[3] = (int)cvtpk(qv[6], qv[7]);
            if (mh == 0) qf0 = __builtin_bit_cast(short8_t, pq);
            else         qf1 = __builtin_bit_cast(short8_t, pq);
        }
    }

    f32x16_t acc00 = {0}, acc01 = {0}, acc10 = {0}, acc11 = {0};  // [mh][et]
    #pragma unroll
    for (int i = 0; i < 16; ++i) { acc00[i]=0.f; acc01[i]=0.f; acc10[i]=0.f; acc11[i]=0.f; }

    short8_t bf00, bf01, bf10, bf11;   // bf[mh][kw] for current step

    // h-MFMA + relu + in-register transpose -> bf[mh][0..1]  (verified R13 network)
    auto htr2 = [&](short8_t af) {
        #pragma unroll
        for (int mh = 0; mh < 2; ++mh) {
            const short8_t qf = (mh == 0) ? qf0 : qf1;
            const f32x16_t z = acc00 * 0.f;
            const f32x16_t d = __builtin_amdgcn_mfma_f32_32x32x16_bf16(af, qf, z, 0, 0, 0);
            unsigned int U00 = cvtpk_hw(fmaxf(d[0],  0.f), fmaxf(d[1],  0.f));
            unsigned int U01 = cvtpk_hw(fmaxf(d[2],  0.f), fmaxf(d[3],  0.f));
            unsigned int U10 = cvtpk_hw(fmaxf(d[4],  0.f), fmaxf(d[5],  0.f));
            unsigned int U11 = cvtpk_hw(fmaxf(d[6],  0.f), fmaxf(d[7],  0.f));
            unsigned int U20 = cvtpk_hw(fmaxf(d[8],  0.f), fmaxf(d[9],  0.f));
            unsigned int U21 = cvtpk_hw(fmaxf(d[10], 0.f), fmaxf(d[11], 0.f));
            unsigned int U30 = cvtpk_hw(fmaxf(d[12], 0.f), fmaxf(d[13], 0.f));
            unsigned int U31 = cvtpk_hw(fmaxf(d[14], 0.f), fmaxf(d[15], 0.f));
            plane32_swap(U00, U10);
            plane32_swap(U01, U11);
            plane32_swap(U20, U30);
            plane32_swap(U21, U31);
            int4_t p0; p0[0]=(int)U00; p0[1]=(int)U01; p0[2]=(int)U10; p0[3]=(int)U11;
            int4_t p1; p1[0]=(int)U20; p1[1]=(int)U21; p1[2]=(int)U30; p1[3]=(int)U31;
            if (mh == 0) { bf00 = __builtin_bit_cast(short8_t, p0);
                           bf01 = __builtin_bit_cast(short8_t, p1); }
            else         { bf10 = __builtin_bit_cast(short8_t, p0);
                           bf11 = __builtin_bit_cast(short8_t, p1); }
        }
    };
    // main: acc[mh][et] += W2f[kw][et] x bf[mh][kw]  (8 MFMA; r = {kw0et0,kw0et1,kw1et0,kw1et1})
    auto main8 = [&](const int4_t& r0, const int4_t& r1, const int4_t& r2, const int4_t& r3) {
        const short8_t w00 = __builtin_bit_cast(short8_t, r0);
        const short8_t w01 = __builtin_bit_cast(short8_t, r1);
        const short8_t w10 = __builtin_bit_cast(short8_t, r2);
        const short8_t w11 = __builtin_bit_cast(short8_t, r3);
        acc00 = __builtin_amdgcn_mfma_f32_32x32x16_bf16(w00, bf00, acc00, 0, 0, 0);
        acc01 = __builtin_amdgcn_mfma_f32_32x32x16_bf16(w01, bf00, acc01, 0, 0, 0);
        acc10 = __builtin_amdgcn_mfma_f32_32x32x16_bf16(w00, bf10, acc10, 0, 0, 0);
        acc11 = __builtin_amdgcn_mfma_f32_32x32x16_bf16(w01, bf10, acc11, 0, 0, 0);
        acc00 = __builtin_amdgcn_mfma_f32_32x32x16_bf16(w10, bf01, acc00, 0, 0, 0);
        acc01 = __builtin_amdgcn_mfma_f32_32x32x16_bf16(w11, bf01, acc01, 0, 0, 0);
        acc10 = __builtin_amdgcn_mfma_f32_32x32x16_bf16(w10, bf11, acc10, 0, 0, 0);
        acc11 = __builtin_amdgcn_mfma_f32_32x32x16_bf16(w11, bf11, acc11, 0, 0, 0);
    };

    if constexpr (WSOK) {
        // per-lane byte bases. W2 frag (ks,et) at byte (ks*8+et)*1024 + lane*16.
        // step s uses ks=2s,2s+1; et=2ct,2ct+1.
        const char* W2b = (const char*)W2t + (size_t)ct * 2048 + (size_t)lane * 16;
        const char* W1a = (const char*)W1b + (size_t)m * 16;

        int4_t c0,c1,c2,c3;     // W2 frags, current step {kw0et0,kw0et1,kw1et0,kw1et1}
        int4_t n0,n1,n2,n3;     // W2 frags, next step
        int4_t afA, afB;

        #define ISSUE_W2(R0,R1,R2,R3, S) do {                                    \
            const char* p0_ = W2b + ((size_t)((S) & 31) << 14);                  \
            const char* p1_ = p0_ + 8192;                                        \
            GLD16O(R0, p0_, "0"); GLD16O(R1, p0_, "1024");                       \
            GLD16O(R2, p1_, "0"); GLD16O(R3, p1_, "1024"); } while (0)
        #define ISSUE_AF(R, S) gld16(R, W1a + ((size_t)((S) & 31) << 9))

        // prologue
        ISSUE_AF(afA, 0);
        wait_all();
        htr2(__builtin_bit_cast(short8_t, afA));   // bf for step 0
        ISSUE_W2(c0,c1,c2,c3, 0);
        ISSUE_AF(afB, 1);
        // invariant entering step s: outstanding = [W2(s) x4, af(s+1) x1]

        #pragma unroll 1
        for (int k = 0; k < 16; ++k) {
            const int s = k * 2;
            // even step s
            ISSUE_W2(n0,n1,n2,n3, s + 1);
            ISSUE_AF(afA, s + 2);
            wait5();                                  // W2(s) + af(s+1) landed
            main8(c0,c1,c2,c3);
            htr2(__builtin_bit_cast(short8_t, afB));  // bf for step s+1
            // odd step s+1
            ISSUE_W2(c0,c1,c2,c3, s + 2);
            ISSUE_AF(afB, s + 3);
            wait5();                                  // W2(s+1) + af(s+2) landed
            main8(n0,n1,n2,n3);
            htr2(__builtin_bit_cast(short8_t, afA));  // bf for s+2 (tail: unused)
        }
        wait_all();   // land dangling wrap prefetches before regalloc reuses their regs
        #undef ISSUE_W2
        #undef ISSUE_AF
    } else {
        // fallback: same math, compiler-scheduled loads + on-the-fly cvt
        for (int s = 0; s < 32; ++s) {
            const float* ws = W1f + (size_t)(s * 32 + m) * 8;
            const float4_t a0 = *reinterpret_cast<const float4_t*>(ws);
            const float4_t a1 = *reinterpret_cast<const float4_t*>(ws + 4);
            int4_t pa;
            pa[0] = (int)cvtpk(a0[0], a0[1]);
            pa[1] = (int)cvtpk(a0[2], a0[3]);
            pa[2] = (int)cvtpk(a1[0], a1[1]);
            pa[3] = (int)cvtpk(a1[2], a1[3]);
            htr2(__builtin_bit_cast(short8_t, pa));
            int4_t fr[4];
            #pragma unroll
            for (int kw = 0; kw < 2; ++kw)
                #pragma unroll
                for (int et = 0; et < 2; ++et) {
                    const int e = ct * 64 + et * 32 + m;
                    const float* p = W2f + (size_t)e * 1024 + (s * 32 + kw * 16) + hi * 8;
                    const float4_t v0 = *reinterpret_cast<const float4_t*>(p);
                    const float4_t v1 = *reinterpret_cast<const float4_t*>(p + 4);
                    int4_t pb;
                    pb[0] = (int)cvtpk(v0[0], v0[1]);
                    pb[1] = (int)cvtpk(v0[2], v0[3]);
                    pb[2] = (int)cvtpk(v1[0], v1[1]);
                    pb[3] = (int)cvtpk(v1[2], v1[3]);
                    fr[kw * 2 + et] = pb;
                }
            main8(fr[0], fr[1], fr[2], fr[3]);
        }
    }

    // ---- epilogue: out^T store. D[e][m]: col m=lane&31, e=(reg&3)+8(reg>>2)+4hi ----
    #define STORE_ET(ACC, MH, ET) do {                                            \
        float* orow = out + (size_t)(rowbase + (MH) * 32 + m) * 256               \
                      + ct * 64 + (ET) * 32 + hi * 4;                             \
        _Pragma("unroll")                                                         \
        for (int rq = 0; rq < 4; ++rq) {                                          \
            float4_t v;                                                           \
            v[0] = ACC[4*rq+0]; v[1] = ACC[4*rq+1];                               \
            v[2] = ACC[4*rq+2]; v[3] = ACC[4*rq+3];                               \
            *reinterpret_cast<float4_t*>(orow + rq * 8) = v;                      \
        } } while (0)
    STORE_ET(acc00, 0, 0);
    STORE_ET(acc01, 0, 1);
    STORE_ET(acc10, 1, 0);
    STORE_ET(acc11, 1, 1);
    #undef STORE_ET
}

extern "C" void kernel_launch(void* const* d_in, const int* in_sizes, int n_in,
                              void* d_out, int out_size, void* d_ws, size_t ws_size,
                              hipStream_t stream) {
    const float* x     = (const float*)d_in[0];   // [8,4096,256]
    const float* theta = (const float*)d_in[1];   // [8]
    const float* W1    = (const float*)d_in[2];   // [1024,8]
    const float* W2    = (const float*)d_in[3];   // [256,1024]
    float* out = (float*)d_out;                   // [8,4096,256] f32

    const size_t need = (size_t)(256 * 1024 + 1024 * 8) * sizeof(unsigned short);
    const bool wsok = (ws_size >= need);

    if (wsok) {
        unsigned short* W2t = (unsigned short*)d_ws;   // 512KB, 32x32x16-A granule layout
        unsigned short* W1b = W2t + 256 * 1024;        // 16KB bf16
        prep_kernel<<<129, 256, 0, stream>>>(W2, W1, W2t, W1b);
        ffq_kernel<true><<<512, 256, 0, stream>>>(x, theta, nullptr, W1b, nullptr, W2t, out);
    } else {
        ffq_kernel<false><<<512, 256, 0, stream>>>(x, theta, W1, nullptr, W2, nullptr, out);
    }
}